// Round 13
// baseline (302.200 us; speedup 1.0000x reference)
//
#include <hip/hip_runtime.h>
#include <hip/hip_fp16.h>

#define HIDDEN 128
#define BSHIFT 9                  // 512 nodes per bucket
#define NBUCK_MAX 256

using f32x4 = __attribute__((ext_vector_type(4))) float;
using f16x8 = __attribute__((ext_vector_type(8))) _Float16;

__device__ __forceinline__ void gload16(const void* g, void* l) {
    __builtin_amdgcn_global_load_lds((const __attribute__((address_space(1))) void*)g,
                                     (__attribute__((address_space(3))) void*)l,
                                     16, 0, 0);
}

// ---------------------------------------------------------------------------
// CSR build (bucketed, no per-node global atomics)
// ---------------------------------------------------------------------------
__global__ void zero_ints(int* __restrict__ a, int n) {
    int i = blockIdx.x * 256 + threadIdx.x;
    if (i < n) a[i] = 0;
}

__launch_bounds__(256)
__global__ void bucket_hist(const int* __restrict__ dst, int* __restrict__ bcnt, int e) {
    __shared__ int c[NBUCK_MAX];
    const int t = threadIdx.x;
    c[t] = 0;
    __syncthreads();
    const int tile0 = blockIdx.x * 4096;
    const int end = min(e, tile0 + 4096);
    for (int i = tile0 + t; i < end; i += 256)
        atomicAdd(&c[dst[i] >> BSHIFT], 1);
    __syncthreads();
    if (c[t]) atomicAdd(&bcnt[t], c[t]);
}

__global__ void scan_buckets(const int* __restrict__ bcnt, int* __restrict__ boffs,
                             int* __restrict__ cursor, int nb) {
    __shared__ int sd[256];
    const int t = threadIdx.x;
    int v = (t < nb) ? bcnt[t] : 0;
    sd[t] = v;
    __syncthreads();
    for (int o = 1; o < 256; o <<= 1) {
        int add = (t >= o) ? sd[t - o] : 0;
        __syncthreads();
        sd[t] += add;
        __syncthreads();
    }
    const int ex = sd[t] - v;
    if (t < nb) { boffs[t] = ex; cursor[t] = ex; }
    if (t == nb - 1) boffs[nb] = ex + v;
}

__launch_bounds__(256)
__global__ void partition_pairs(const int* __restrict__ src, const int* __restrict__ dst,
                                int* __restrict__ cursor,
                                unsigned long long* __restrict__ pairs, int e) {
    __shared__ int cnt[NBUCK_MAX];
    __shared__ int base[NBUCK_MAX];
    const int t = threadIdx.x;
    const int tile0 = blockIdx.x * 4096;
    cnt[t] = 0;
    __syncthreads();
    int s[16], d[16], b[16];
    #pragma unroll
    for (int j = 0; j < 16; ++j) {
        const int i = tile0 + j * 256 + t;
        if (i < e) {
            d[j] = dst[i];
            s[j] = src[i];
            b[j] = d[j] >> BSHIFT;
            atomicAdd(&cnt[b[j]], 1);
        } else {
            b[j] = -1;
        }
    }
    __syncthreads();
    const int c = cnt[t];
    base[t] = c ? atomicAdd(&cursor[t], c) : 0;
    __syncthreads();
    cnt[t] = 0;
    __syncthreads();
    #pragma unroll
    for (int j = 0; j < 16; ++j) {
        if (b[j] >= 0) {
            const int r = atomicAdd(&cnt[b[j]], 1);
            pairs[(size_t)base[b[j]] + r] =
                ((unsigned long long)(unsigned)d[j] << 32) | (unsigned)s[j];
        }
    }
}

__launch_bounds__(256)
__global__ void place_csr2(const unsigned long long* __restrict__ pairs,
                           const int* __restrict__ boffs,
                           int* __restrict__ offs, int* __restrict__ csr,
                           int n, int e) {
    __shared__ int cnt[1 << BSHIFT];
    __shared__ int sc[256];
    const int b = blockIdx.x;
    const int t = threadIdx.x;
    const int node0 = b << BSHIFT;
    const int nn = min(1 << BSHIFT, n - node0);
    cnt[t] = 0;
    cnt[t + 256] = 0;
    __syncthreads();
    const int beg = boffs[b], end = boffs[b + 1];
    for (int i = beg + t; i < end; i += 256)
        atomicAdd(&cnt[(int)(pairs[i] >> 32) - node0], 1);
    __syncthreads();
    const int a0 = cnt[2 * t], a1 = cnt[2 * t + 1];
    const int s = a0 + a1;
    sc[t] = s;
    __syncthreads();
    for (int o = 1; o < 256; o <<= 1) {
        int add = (t >= o) ? sc[t - o] : 0;
        __syncthreads();
        sc[t] += add;
        __syncthreads();
    }
    const int g0 = beg + sc[t] - s;
    const int g1 = g0 + a0;
    if (2 * t < nn)     offs[node0 + 2 * t] = g0;
    if (2 * t + 1 < nn) offs[node0 + 2 * t + 1] = g1;
    __syncthreads();
    cnt[2 * t] = g0;
    cnt[2 * t + 1] = g1;
    if (node0 + nn == n && t == 0) offs[n] = e;   // sentinel
    __syncthreads();
    for (int i = beg + t; i < end; i += 256) {
        const unsigned long long pr = pairs[i];
        const int dd = (int)(pr >> 32) - node0;
        const int ss = (int)(unsigned)pr;
        const int p = atomicAdd(&cnt[dd], 1);
        csr[p] = ss;
    }
}

// ---------------------------------------------------------------------------
// Pack weights into MFMA-fragment-ordered f16 planes (Wh + Wls*32).
// ---------------------------------------------------------------------------
__global__ void pack_weights(const float* __restrict__ W_t, const float* __restrict__ Ws0,
                             const float* __restrict__ Wn0, const float* __restrict__ Ws1,
                             const float* __restrict__ Wn1,
                             __half* p_t, __half* p_l0, __half* p_l1) {
    const int bid = blockIdx.x;
    const float* W; __half* out; int b0; int S0;
    if (bid < 16)      { W = W_t; out = p_t;  b0 = 0;  S0 = 0; }
    else if (bid < 24) { W = Ws0; out = p_l0; b0 = 16; S0 = 0; }
    else if (bid < 32) { W = Wn0; out = p_l0; b0 = 24; S0 = 4; }
    else if (bid < 40) { W = Ws1; out = p_l1; b0 = 32; S0 = 0; }
    else               { W = Wn1; out = p_l1; b0 = 40; S0 = 4; }
    const int idx = (bid - b0) * 256 + threadIdx.x;
    const int step = idx >> 9;
    const int r = idx & 511;
    const int l = r & 63;
    const int col = (r >> 6) * 16 + (l & 15);
    const int k0 = step * 32 + ((l >> 4) << 3);
    const size_t o = (size_t)(S0 + step) * 4096 + (size_t)r * 8;
    #pragma unroll
    for (int j = 0; j < 8; ++j) {
        float f = W[(k0 + j) * HIDDEN + col];
        __half h = __float2half_rn(f);
        out[o + j] = h;
        out[32768 + o + j] = __float2half_rn((f - __half2float(h)) * 32.0f);
    }
}

// ---------------------------------------------------------------------------
// Streaming cast: x (f32) -> x16 (fp16 RNE). Pure bandwidth kernel:
// 32B read + 16B write per thread per iter, grid-stride, full MLP.
// ---------------------------------------------------------------------------
__launch_bounds__(256)
__global__ void cast_x16(const float* __restrict__ x, __half* __restrict__ x16, long n) {
    const long stride = (long)gridDim.x * 256 * 8;
    for (long i = ((long)blockIdx.x * 256 + threadIdx.x) * 8; i < n; i += stride) {
        f32x4 a = *(const f32x4*)(x + i);
        f32x4 b = *(const f32x4*)(x + i + 4);
        __half2 h[4];
        h[0] = __floats2half2_rn(a[0], a[1]);
        h[1] = __floats2half2_rn(a[2], a[3]);
        h[2] = __floats2half2_rn(b[0], b[1]);
        h[3] = __floats2half2_rn(b[2], b[3]);
        uint4 o;
        o.x = *(unsigned*)&h[0];
        o.y = *(unsigned*)&h[1];
        o.z = *(unsigned*)&h[2];
        o.w = *(unsigned*)&h[3];
        *(uint4*)&x16[i] = o;
    }
}

// ---------------------------------------------------------------------------
// GEMM, max occupancy: 32-row tile (16 KB LDS), VGPR<=64 via
// __launch_bounds__(256,8). 4 waves col-split (32 cols each). Single DMA
// burst + ONE barrier + barrier-free K-loop. acc += A*Wh + (A*2^-5)*Wls.
// A = [A0 | A1], each K=128 slab addressed with row stride `lda`:
//   layers:    A0=h, A1=agg, lda=128
//   transform: A0=x16, A1=x16+128, lda=256  (one K=256 matrix)
// ---------------------------------------------------------------------------
template <bool RELU, bool FINAL>
__launch_bounds__(256, 8)
__global__ void gemm32(const __half* __restrict__ A0, const __half* __restrict__ A1,
                       const __half* __restrict__ Wp,
                       const float* __restrict__ bias,
                       const float* __restrict__ wfin,
                       void* __restrict__ outv, int nrows, int lda) {
    __shared__ __align__(16) __half As[8][2][64][8];   // [step][rt][lane][8] = 16 KB
    __shared__ float red[FINAL ? 32 : 1][4];

    const int t = threadIdx.x;
    const int lane = t & 63;
    const int w = t >> 6;
    const int blockRow0 = blockIdx.x * 32;

    // burst-stage: wave w stages steps {2w, 2w+1} x rt {0,1} (4 DMAs/wave)
    {
        const int koff = (lane >> 4) << 3;
        #pragma unroll
        for (int i = 0; i < 2; ++i) {
            const int step = w * 2 + i;
            const __half* Abase = (step < 4) ? A0 : A1;
            const int kk = (step & 3) * 32 + koff;
            #pragma unroll
            for (int rt = 0; rt < 2; ++rt) {
                const int row = min(blockRow0 + rt * 16 + (lane & 15), nrows - 1);
                gload16(Abase + (size_t)row * lda + kk, &As[step][rt][0][0]);
            }
        }
    }
    __syncthreads();   // single drain; LDS read-only afterwards

    f32x4 acc[2][2];
    #pragma unroll
    for (int i = 0; i < 2; ++i)
        #pragma unroll
        for (int j = 0; j < 2; ++j) acc[i][j] = (f32x4){0.f, 0.f, 0.f, 0.f};

    const _Float16 S = (_Float16)0.03125f;   // 2^-5

    #pragma unroll
    for (int step = 0; step < 8; ++step) {
        const __half* wb = Wp + (size_t)step * 4096 + (w * 2) * 512 + lane * 8;
        f16x8 a[2], asr[2];
        #pragma unroll
        for (int rt = 0; rt < 2; ++rt) {
            a[rt] = *(const f16x8*)&As[step][rt][lane][0];
            asr[rt] = a[rt] * S;
        }
        #pragma unroll
        for (int c2 = 0; c2 < 2; ++c2) {
            f16x8 wh = *(const f16x8*)(wb + c2 * 512);
            f16x8 wl = *(const f16x8*)(wb + 32768 + c2 * 512);
            acc[0][c2] = __builtin_amdgcn_mfma_f32_16x16x32_f16(a[0], wh, acc[0][c2], 0, 0, 0);
            acc[1][c2] = __builtin_amdgcn_mfma_f32_16x16x32_f16(a[1], wh, acc[1][c2], 0, 0, 0);
            acc[0][c2] = __builtin_amdgcn_mfma_f32_16x16x32_f16(asr[0], wl, acc[0][c2], 0, 0, 0);
            acc[1][c2] = __builtin_amdgcn_mfma_f32_16x16x32_f16(asr[1], wl, acc[1][c2], 0, 0, 0);
        }
    }

    if constexpr (FINAL) {
        // fused out = relu(acc + bias) @ wfin; cross-wave col reduction via LDS
        float part[2][4];
        #pragma unroll
        for (int rt = 0; rt < 2; ++rt)
            #pragma unroll
            for (int j = 0; j < 4; ++j) part[rt][j] = 0.f;
        #pragma unroll
        for (int c2 = 0; c2 < 2; ++c2) {
            const int col = w * 32 + c2 * 16 + (lane & 15);
            const float wf = wfin[col];
            const float bc = bias[col];
            #pragma unroll
            for (int rt = 0; rt < 2; ++rt)
                #pragma unroll
                for (int j = 0; j < 4; ++j) {
                    float v = acc[rt][c2][j] + bc;
                    if (RELU) v = fmaxf(v, 0.f);
                    part[rt][j] = fmaf(v, wf, part[rt][j]);
                }
        }
        #pragma unroll
        for (int o = 1; o < 16; o <<= 1)
            #pragma unroll
            for (int rt = 0; rt < 2; ++rt)
                #pragma unroll
                for (int j = 0; j < 4; ++j)
                    part[rt][j] += __shfl_xor(part[rt][j], o, 64);
        if ((lane & 15) == 0) {
            #pragma unroll
            for (int rt = 0; rt < 2; ++rt)
                #pragma unroll
                for (int j = 0; j < 4; ++j)
                    red[rt * 16 + ((lane >> 4) << 2) + j][w] = part[rt][j];
        }
        __syncthreads();
        if (t < 32) {
            const int r = blockRow0 + t;
            if (r < nrows)
                ((float*)outv)[r] = red[t][0] + red[t][1] + red[t][2] + red[t][3];
        }
    } else {
        __half* out = (__half*)outv;
        #pragma unroll
        for (int c2 = 0; c2 < 2; ++c2) {
            const int col = w * 32 + c2 * 16 + (lane & 15);
            const float bc = bias[col];
            #pragma unroll
            for (int rt = 0; rt < 2; ++rt) {
                const int r0 = blockRow0 + rt * 16 + ((lane >> 4) << 2);
                #pragma unroll
                for (int j = 0; j < 4; ++j) {
                    const int r = r0 + j;
                    if (r < nrows) {
                        float v = acc[rt][c2][j] + bc;
                        if (RELU) v = fmaxf(v, 0.f);
                        out[(size_t)r * HIDDEN + col] = __float2half(v);
                    }
                }
            }
        }
    }
}

// ---------------------------------------------------------------------------
// Neighbor mean over fp16 h. One wave per node; 4 edge slots, full-row uint4
// loads; deg = offs[node+1] - offs[node].
// ---------------------------------------------------------------------------
__global__ void aggregate_h16(const __half* __restrict__ h, const int* __restrict__ offs,
                              const int* __restrict__ csr,
                              __half* __restrict__ agg, int n) {
    const int node = blockIdx.x * 4 + (threadIdx.x >> 6);
    if (node >= n) return;
    const int lane = threadIdx.x & 63;
    const int slot = lane >> 4;          // edge slot (0..3)
    const int c8 = (lane & 15) * 8;      // 8 cols per lane
    const int start = offs[node];
    const int d = offs[node + 1] - start;
    float a[8] = {0.f, 0.f, 0.f, 0.f, 0.f, 0.f, 0.f, 0.f};
    for (int i = slot; i < d; i += 16) {
        #pragma unroll
        for (int u = 0; u < 4; ++u) {
            const int e = i + u * 4;
            if (e < d) {
                const int s = csr[start + e];
                uint4 raw = *(const uint4*)&h[(size_t)s * HIDDEN + c8];
                const __half2* hp = (const __half2*)&raw;
                #pragma unroll
                for (int m = 0; m < 4; ++m) {
                    float2 f = __half22float2(hp[m]);
                    a[2 * m] += f.x;
                    a[2 * m + 1] += f.y;
                }
            }
        }
    }
    #pragma unroll
    for (int k = 0; k < 8; ++k) {
        a[k] += __shfl_xor(a[k], 16, 64);
        a[k] += __shfl_xor(a[k], 32, 64);
    }
    if (slot == 0) {
        const float inv = 1.0f / (float)max(d, 1);
        uint4 raw;
        __half2* op = (__half2*)&raw;
        #pragma unroll
        for (int m = 0; m < 4; ++m)
            op[m] = __floats2half2_rn(a[2 * m] * inv, a[2 * m + 1] * inv);
        *(uint4*)&agg[(size_t)node * HIDDEN + c8] = raw;
    }
}

// ---------------------------------------------------------------------------
extern "C" void kernel_launch(void* const* d_in, const int* in_sizes, int n_in,
                              void* d_out, int out_size, void* d_ws, size_t ws_size,
                              hipStream_t stream) {
    const float* x     = (const float*)d_in[0];
    const float* W_t   = (const float*)d_in[1];
    const float* b_t   = (const float*)d_in[2];
    const float* W_s0  = (const float*)d_in[3];
    const float* b_s0  = (const float*)d_in[4];
    const float* W_n0  = (const float*)d_in[5];
    const float* W_s1  = (const float*)d_in[6];
    const float* b_s1  = (const float*)d_in[7];
    const float* W_n1  = (const float*)d_in[8];
    const float* W_fin = (const float*)d_in[9];
    const int*   src   = (const int*)d_in[10];
    const int*   dst   = (const int*)d_in[11];
    float* out = (float*)d_out;

    const int N = in_sizes[0] / 256;   // 100000
    const int E = in_sizes[10];        // 1600000

    size_t off_b = 0;
    auto carve = [&](size_t bytes) {
        size_t cur = off_b;
        off_b = (off_b + bytes + 255) & ~(size_t)255;
        return cur;
    };
    char* base = (char*)d_ws;
    int* offs   = (int*)(base + carve((size_t)(N + 1) * 4));
    int* bcnt   = (int*)(base + carve(NBUCK_MAX * 4));
    int* boffs  = (int*)(base + carve((NBUCK_MAX + 1) * 4));
    int* cursor = (int*)(base + carve(NBUCK_MAX * 4));
    int* csr    = (int*)(base + carve((size_t)E * 4));
    unsigned long long* pairs = (unsigned long long*)(base + carve((size_t)E * 8));
    __half* wp_t  = (__half*)(base + carve((size_t)65536 * 2));
    __half* wp_l0 = (__half*)(base + carve((size_t)65536 * 2));
    __half* wp_l1 = (__half*)(base + carve((size_t)65536 * 2));
    __half* x16 = (__half*)(base + carve((size_t)N * 256 * 2));
    __half* hA  = (__half*)(base + carve((size_t)N * HIDDEN * 2));
    __half* hB  = (__half*)(base + carve((size_t)N * HIDDEN * 2));
    __half* agp = (__half*)(base + carve((size_t)N * HIDDEN * 2));
    (void)ws_size; (void)n_in; (void)out_size;

    const int nBuck = (N + (1 << BSHIFT) - 1) >> BSHIFT;   // 196

    // --- CSR build (bucketed) ---
    hipLaunchKernelGGL(zero_ints, dim3(1), dim3(256), 0, stream, bcnt, NBUCK_MAX);
    hipLaunchKernelGGL(bucket_hist, dim3((E + 4095) / 4096), dim3(256), 0, stream, dst, bcnt, E);
    hipLaunchKernelGGL(scan_buckets, dim3(1), dim3(256), 0, stream, bcnt, boffs, cursor, nBuck);
    hipLaunchKernelGGL(partition_pairs, dim3((E + 4095) / 4096), dim3(256), 0, stream,
                       src, dst, cursor, pairs, E);
    hipLaunchKernelGGL(place_csr2, dim3(nBuck), dim3(256), 0, stream, pairs, boffs, offs, csr, N, E);

    // --- weight packing (48 tiny blocks) + x cast ---
    hipLaunchKernelGGL(pack_weights, dim3(48), dim3(256), 0, stream,
                       W_t, W_s0, W_n0, W_s1, W_n1, wp_t, wp_l0, wp_l1);
    hipLaunchKernelGGL(cast_x16, dim3(2048), dim3(256), 0, stream,
                       x, x16, (long)N * 256);

    const int g32 = (N + 31) / 32;     // 3125
    const int nodeGrid = (N + 3) / 4;

    // h0 = x @ W_t + b_t  (transform as a layer GEMM over fp16 x)
    hipLaunchKernelGGL((gemm32<false, false>), dim3(g32), dim3(256), 0, stream,
                       x16, x16 + 128, wp_t, b_t, (const float*)nullptr, (void*)hA, N, 256);
    // layer 0
    hipLaunchKernelGGL(aggregate_h16, dim3(nodeGrid), dim3(256), 0, stream, hA, offs, csr, agp, N);
    hipLaunchKernelGGL((gemm32<true, false>), dim3(g32), dim3(256), 0, stream,
                       hA, agp, wp_l0, b_s0, (const float*)nullptr, (void*)hB, N, 128);
    // layer 1 + fused final projection
    hipLaunchKernelGGL(aggregate_h16, dim3(nodeGrid), dim3(256), 0, stream, hB, offs, csr, agp, N);
    hipLaunchKernelGGL((gemm32<true, true>), dim3(g32), dim3(256), 0, stream,
                       hB, agp, wp_l1, b_s1, W_fin, (void*)out, N, 128);
}

// Round 14
// 277.274 us; speedup vs baseline: 1.0899x; 1.0899x over previous
//
#include <hip/hip_runtime.h>
#include <hip/hip_fp16.h>

#define HIDDEN 128
#define BSHIFT 9                  // 512 nodes per bucket
#define NBUCK_MAX 256

using f32x4 = __attribute__((ext_vector_type(4))) float;
using f16x8 = __attribute__((ext_vector_type(8))) _Float16;

__device__ __forceinline__ void gload16(const void* g, void* l) {
    __builtin_amdgcn_global_load_lds((const __attribute__((address_space(1))) void*)g,
                                     (__attribute__((address_space(3))) void*)l,
                                     16, 0, 0);
}

// ---------------------------------------------------------------------------
// CSR build (bucketed, no per-node global atomics)
// ---------------------------------------------------------------------------
__global__ void zero_ints(int* __restrict__ a, int n) {
    int i = blockIdx.x * 256 + threadIdx.x;
    if (i < n) a[i] = 0;
}

__launch_bounds__(256)
__global__ void bucket_hist(const int* __restrict__ dst, int* __restrict__ bcnt, int e) {
    __shared__ int c[NBUCK_MAX];
    const int t = threadIdx.x;
    c[t] = 0;
    __syncthreads();
    const int tile0 = blockIdx.x * 4096;
    const int end = min(e, tile0 + 4096);
    for (int i = tile0 + t; i < end; i += 256)
        atomicAdd(&c[dst[i] >> BSHIFT], 1);
    __syncthreads();
    if (c[t]) atomicAdd(&bcnt[t], c[t]);
}

__global__ void scan_buckets(const int* __restrict__ bcnt, int* __restrict__ boffs,
                             int* __restrict__ cursor, int nb) {
    __shared__ int sd[256];
    const int t = threadIdx.x;
    int v = (t < nb) ? bcnt[t] : 0;
    sd[t] = v;
    __syncthreads();
    for (int o = 1; o < 256; o <<= 1) {
        int add = (t >= o) ? sd[t - o] : 0;
        __syncthreads();
        sd[t] += add;
        __syncthreads();
    }
    const int ex = sd[t] - v;
    if (t < nb) { boffs[t] = ex; cursor[t] = ex; }
    if (t == nb - 1) boffs[nb] = ex + v;
}

__launch_bounds__(256)
__global__ void partition_pairs(const int* __restrict__ src, const int* __restrict__ dst,
                                int* __restrict__ cursor,
                                unsigned long long* __restrict__ pairs, int e) {
    __shared__ int cnt[NBUCK_MAX];
    __shared__ int base[NBUCK_MAX];
    const int t = threadIdx.x;
    const int tile0 = blockIdx.x * 4096;
    cnt[t] = 0;
    __syncthreads();
    int s[16], d[16], b[16];
    #pragma unroll
    for (int j = 0; j < 16; ++j) {
        const int i = tile0 + j * 256 + t;
        if (i < e) {
            d[j] = dst[i];
            s[j] = src[i];
            b[j] = d[j] >> BSHIFT;
            atomicAdd(&cnt[b[j]], 1);
        } else {
            b[j] = -1;
        }
    }
    __syncthreads();
    const int c = cnt[t];
    base[t] = c ? atomicAdd(&cursor[t], c) : 0;
    __syncthreads();
    cnt[t] = 0;
    __syncthreads();
    #pragma unroll
    for (int j = 0; j < 16; ++j) {
        if (b[j] >= 0) {
            const int r = atomicAdd(&cnt[b[j]], 1);
            pairs[(size_t)base[b[j]] + r] =
                ((unsigned long long)(unsigned)d[j] << 32) | (unsigned)s[j];
        }
    }
}

__launch_bounds__(256)
__global__ void place_csr2(const unsigned long long* __restrict__ pairs,
                           const int* __restrict__ boffs,
                           int* __restrict__ offs, int* __restrict__ csr,
                           int n, int e) {
    __shared__ int cnt[1 << BSHIFT];
    __shared__ int sc[256];
    const int b = blockIdx.x;
    const int t = threadIdx.x;
    const int node0 = b << BSHIFT;
    const int nn = min(1 << BSHIFT, n - node0);
    cnt[t] = 0;
    cnt[t + 256] = 0;
    __syncthreads();
    const int beg = boffs[b], end = boffs[b + 1];
    for (int i = beg + t; i < end; i += 256)
        atomicAdd(&cnt[(int)(pairs[i] >> 32) - node0], 1);
    __syncthreads();
    const int a0 = cnt[2 * t], a1 = cnt[2 * t + 1];
    const int s = a0 + a1;
    sc[t] = s;
    __syncthreads();
    for (int o = 1; o < 256; o <<= 1) {
        int add = (t >= o) ? sc[t - o] : 0;
        __syncthreads();
        sc[t] += add;
        __syncthreads();
    }
    const int g0 = beg + sc[t] - s;
    const int g1 = g0 + a0;
    if (2 * t < nn)     offs[node0 + 2 * t] = g0;
    if (2 * t + 1 < nn) offs[node0 + 2 * t + 1] = g1;
    __syncthreads();
    cnt[2 * t] = g0;
    cnt[2 * t + 1] = g1;
    if (node0 + nn == n && t == 0) offs[n] = e;   // sentinel
    __syncthreads();
    for (int i = beg + t; i < end; i += 256) {
        const unsigned long long pr = pairs[i];
        const int dd = (int)(pr >> 32) - node0;
        const int ss = (int)(unsigned)pr;
        const int p = atomicAdd(&cnt[dd], 1);
        csr[p] = ss;
    }
}

// ---------------------------------------------------------------------------
// Pack weights into MFMA-fragment-ordered f16 planes (Wh + Wls*32).
// ---------------------------------------------------------------------------
__global__ void pack_weights(const float* __restrict__ W_t, const float* __restrict__ Ws0,
                             const float* __restrict__ Wn0, const float* __restrict__ Ws1,
                             const float* __restrict__ Wn1,
                             __half* p_t, __half* p_l0, __half* p_l1) {
    const int bid = blockIdx.x;
    const float* W; __half* out; int b0; int S0;
    if (bid < 16)      { W = W_t; out = p_t;  b0 = 0;  S0 = 0; }
    else if (bid < 24) { W = Ws0; out = p_l0; b0 = 16; S0 = 0; }
    else if (bid < 32) { W = Wn0; out = p_l0; b0 = 24; S0 = 4; }
    else if (bid < 40) { W = Ws1; out = p_l1; b0 = 32; S0 = 0; }
    else               { W = Wn1; out = p_l1; b0 = 40; S0 = 4; }
    const int idx = (bid - b0) * 256 + threadIdx.x;
    const int step = idx >> 9;
    const int r = idx & 511;
    const int l = r & 63;
    const int col = (r >> 6) * 16 + (l & 15);
    const int k0 = step * 32 + ((l >> 4) << 3);
    const size_t o = (size_t)(S0 + step) * 4096 + (size_t)r * 8;
    #pragma unroll
    for (int j = 0; j < 8; ++j) {
        float f = W[(k0 + j) * HIDDEN + col];
        __half h = __float2half_rn(f);
        out[o + j] = h;
        out[32768 + o + j] = __float2half_rn((f - __half2float(h)) * 32.0f);
    }
}

// ---------------------------------------------------------------------------
// FUSED SAGE layer: 32 dst rows per block. A-tile K=256 = [h self | agg].
//  1) fire self-half DMAs (steps 0-3) into LDS
//  2) each wave gathers+means 8 of the 32 nodes, writing agg DIRECTLY into
//     the MFMA fragment layout (steps 4-7): lane l (cols 8l..8l+7 of row r)
//     -> As[4+(l>>2)][r>>4][(r&15) + 16*(l&3)][0..7]
//  3) ONE barrier, 4) barrier-free K-loop: acc += A*Wh + (A*2^-5)*Wls.
// ---------------------------------------------------------------------------
template <bool RELU, bool FINAL>
__launch_bounds__(256, 8)
__global__ void sage32(const __half* __restrict__ h,
                       const int* __restrict__ offs, const int* __restrict__ csr,
                       const __half* __restrict__ Wp,
                       const float* __restrict__ bias,
                       const float* __restrict__ wfin,
                       void* __restrict__ outv, int nrows) {
    __shared__ __align__(16) __half As[8][2][64][8];   // 16 KB
    __shared__ float red[FINAL ? 32 : 1][4];

    const int t = threadIdx.x;
    const int lane = t & 63;
    const int w = t >> 6;
    const int blockRow0 = blockIdx.x * 32;

    // 1) self-half DMA: wave w stages step w (k = w*32..w*32+32), rt 0,1
    {
        const int kk = w * 32 + ((lane >> 4) << 3);
        #pragma unroll
        for (int rt = 0; rt < 2; ++rt) {
            const int row = min(blockRow0 + rt * 16 + (lane & 15), nrows - 1);
            gload16(h + (size_t)row * HIDDEN + kk, &As[w][rt][0][0]);
        }
    }

    // 2) gather phase: wave w aggregates nodes blockRow0 + w*8 + [0,8)
    {
        const int slot = lane >> 4;          // 0..3
        const int c8 = (lane & 15) * 8;      // 8 cols per lane
        #pragma unroll 1
        for (int nd = 0; nd < 8; ++nd) {
            const int rl = w * 8 + nd;       // local row 0..31
            const int node = min(blockRow0 + rl, nrows - 1);
            const int start = offs[node];
            const int d = offs[node + 1] - start;
            float a[8] = {0.f, 0.f, 0.f, 0.f, 0.f, 0.f, 0.f, 0.f};
            for (int i = slot; i < d; i += 16) {
                #pragma unroll
                for (int u = 0; u < 4; ++u) {
                    const int e = i + u * 4;
                    if (e < d) {
                        const int s = csr[start + e];
                        uint4 raw = *(const uint4*)&h[(size_t)s * HIDDEN + c8];
                        const __half2* hp = (const __half2*)&raw;
                        #pragma unroll
                        for (int m = 0; m < 4; ++m) {
                            float2 f = __half22float2(hp[m]);
                            a[2 * m] += f.x;
                            a[2 * m + 1] += f.y;
                        }
                    }
                }
            }
            #pragma unroll
            for (int k = 0; k < 8; ++k) {
                a[k] += __shfl_xor(a[k], 16, 64);
                a[k] += __shfl_xor(a[k], 32, 64);
            }
            if (slot == 0) {
                const float inv = 1.0f / (float)max(d, 1);
                f16x8 v;
                #pragma unroll
                for (int j = 0; j < 8; ++j) v[j] = (_Float16)(a[j] * inv);
                // fragment-layout write (see header comment)
                *(f16x8*)&As[4 + (lane >> 2)][rl >> 4][(rl & 15) + 16 * (lane & 3)][0] = v;
            }
        }
    }
    __syncthreads();   // drains DMA + gather writes; LDS read-only afterwards

    // 3) K-loop (identical to gemm32)
    f32x4 acc[2][2];
    #pragma unroll
    for (int i = 0; i < 2; ++i)
        #pragma unroll
        for (int j = 0; j < 2; ++j) acc[i][j] = (f32x4){0.f, 0.f, 0.f, 0.f};

    const _Float16 S = (_Float16)0.03125f;   // 2^-5

    #pragma unroll
    for (int step = 0; step < 8; ++step) {
        const __half* wb = Wp + (size_t)step * 4096 + (w * 2) * 512 + lane * 8;
        f16x8 a[2], asr[2];
        #pragma unroll
        for (int rt = 0; rt < 2; ++rt) {
            a[rt] = *(const f16x8*)&As[step][rt][lane][0];
            asr[rt] = a[rt] * S;
        }
        #pragma unroll
        for (int c2 = 0; c2 < 2; ++c2) {
            f16x8 wh = *(const f16x8*)(wb + c2 * 512);
            f16x8 wl = *(const f16x8*)(wb + 32768 + c2 * 512);
            acc[0][c2] = __builtin_amdgcn_mfma_f32_16x16x32_f16(a[0], wh, acc[0][c2], 0, 0, 0);
            acc[1][c2] = __builtin_amdgcn_mfma_f32_16x16x32_f16(a[1], wh, acc[1][c2], 0, 0, 0);
            acc[0][c2] = __builtin_amdgcn_mfma_f32_16x16x32_f16(asr[0], wl, acc[0][c2], 0, 0, 0);
            acc[1][c2] = __builtin_amdgcn_mfma_f32_16x16x32_f16(asr[1], wl, acc[1][c2], 0, 0, 0);
        }
    }

    // 4) epilogue
    if constexpr (FINAL) {
        float part[2][4];
        #pragma unroll
        for (int rt = 0; rt < 2; ++rt)
            #pragma unroll
            for (int j = 0; j < 4; ++j) part[rt][j] = 0.f;
        #pragma unroll
        for (int c2 = 0; c2 < 2; ++c2) {
            const int col = w * 32 + c2 * 16 + (lane & 15);
            const float wf = wfin[col];
            const float bc = bias[col];
            #pragma unroll
            for (int rt = 0; rt < 2; ++rt)
                #pragma unroll
                for (int j = 0; j < 4; ++j) {
                    float v = acc[rt][c2][j] + bc;
                    if (RELU) v = fmaxf(v, 0.f);
                    part[rt][j] = fmaf(v, wf, part[rt][j]);
                }
        }
        #pragma unroll
        for (int o = 1; o < 16; o <<= 1)
            #pragma unroll
            for (int rt = 0; rt < 2; ++rt)
                #pragma unroll
                for (int j = 0; j < 4; ++j)
                    part[rt][j] += __shfl_xor(part[rt][j], o, 64);
        if ((lane & 15) == 0) {
            #pragma unroll
            for (int rt = 0; rt < 2; ++rt)
                #pragma unroll
                for (int j = 0; j < 4; ++j)
                    red[rt * 16 + ((lane >> 4) << 2) + j][w] = part[rt][j];
        }
        __syncthreads();
        if (t < 32) {
            const int r = blockRow0 + t;
            if (r < nrows)
                ((float*)outv)[r] = red[t][0] + red[t][1] + red[t][2] + red[t][3];
        }
    } else {
        __half* out = (__half*)outv;
        #pragma unroll
        for (int c2 = 0; c2 < 2; ++c2) {
            const int col = w * 32 + c2 * 16 + (lane & 15);
            const float bc = bias[col];
            #pragma unroll
            for (int rt = 0; rt < 2; ++rt) {
                const int r0 = blockRow0 + rt * 16 + ((lane >> 4) << 2);
                #pragma unroll
                for (int j = 0; j < 4; ++j) {
                    const int r = r0 + j;
                    if (r < nrows) {
                        float v = acc[rt][c2][j] + bc;
                        if (RELU) v = fmaxf(v, 0.f);
                        out[(size_t)r * HIDDEN + col] = __float2half(v);
                    }
                }
            }
        }
    }
}

// ---------------------------------------------------------------------------
// Transform GEMM (R11 winner): 32-row f32 tile (32 KB LDS), 4 waves
// col-split, single DMA burst + ONE barrier; f32->f16 cvt at read.
// ---------------------------------------------------------------------------
__launch_bounds__(256, 4)
__global__ void gemm_x32v(const float* __restrict__ X, const __half* __restrict__ Wp,
                          const float* __restrict__ bias,
                          __half* __restrict__ outp, int nrows) {
    __shared__ __align__(16) float Xs[8][2][2][64][4];   // [step][rt][half][lane][4] = 32 KB

    const int t = threadIdx.x;
    const int lane = t & 63;
    const int w = t >> 6;
    const int blockRow0 = blockIdx.x * 32;

    // burst-stage: wave w stages rt = w>>1, half = w&1 for all 8 steps (8 DMAs)
    {
        const int rt = w >> 1, hf = w & 1;
        const int row = min(blockRow0 + rt * 16 + (lane & 15), nrows - 1);
        const int k0 = ((lane >> 4) << 3) + hf * 4;
        #pragma unroll
        for (int step = 0; step < 8; ++step) {
            const float* src = X + (size_t)row * 256 + step * 32 + k0;
            gload16(src, &Xs[step][rt][hf][0][0]);
        }
    }
    __syncthreads();   // single drain

    f32x4 acc[2][2];
    #pragma unroll
    for (int i = 0; i < 2; ++i)
        #pragma unroll
        for (int j = 0; j < 2; ++j) acc[i][j] = (f32x4){0.f, 0.f, 0.f, 0.f};

    const _Float16 S = (_Float16)0.03125f;   // 2^-5

    #pragma unroll
    for (int step = 0; step < 8; ++step) {
        const __half* wb = Wp + (size_t)step * 4096 + (w * 2) * 512 + lane * 8;
        f16x8 wh[2], wl[2];
        #pragma unroll
        for (int c2 = 0; c2 < 2; ++c2) {
            wh[c2] = *(const f16x8*)(wb + c2 * 512);
            wl[c2] = *(const f16x8*)(wb + 32768 + c2 * 512);
        }
        f16x8 a[2], asr[2];
        #pragma unroll
        for (int r2 = 0; r2 < 2; ++r2) {
            f32x4 x0 = *(const f32x4*)&Xs[step][r2][0][lane][0];
            f32x4 x1 = *(const f32x4*)&Xs[step][r2][1][lane][0];
            f16x8 hh;
            #pragma unroll
            for (int j = 0; j < 4; ++j) hh[j] = (_Float16)x0[j];
            #pragma unroll
            for (int j = 0; j < 4; ++j) hh[4 + j] = (_Float16)x1[j];
            a[r2] = hh;
            asr[r2] = hh * S;
        }
        #pragma unroll
        for (int r2 = 0; r2 < 2; ++r2)
            #pragma unroll
            for (int c2 = 0; c2 < 2; ++c2) {
                acc[r2][c2] = __builtin_amdgcn_mfma_f32_16x16x32_f16(a[r2], wh[c2], acc[r2][c2], 0, 0, 0);
                acc[r2][c2] = __builtin_amdgcn_mfma_f32_16x16x32_f16(asr[r2], wl[c2], acc[r2][c2], 0, 0, 0);
            }
    }

    // epilogue: bias, fp16 h store
    #pragma unroll
    for (int c2 = 0; c2 < 2; ++c2) {
        const int col = w * 32 + c2 * 16 + (lane & 15);
        const float bc = bias[col];
        #pragma unroll
        for (int r2 = 0; r2 < 2; ++r2) {
            const int r0 = blockRow0 + r2 * 16 + ((lane >> 4) << 2);
            #pragma unroll
            for (int j = 0; j < 4; ++j) {
                const int r = r0 + j;
                if (r < nrows)
                    outp[(size_t)r * HIDDEN + col] = __float2half(acc[r2][c2][j] + bc);
            }
        }
    }
}

// ---------------------------------------------------------------------------
extern "C" void kernel_launch(void* const* d_in, const int* in_sizes, int n_in,
                              void* d_out, int out_size, void* d_ws, size_t ws_size,
                              hipStream_t stream) {
    const float* x     = (const float*)d_in[0];
    const float* W_t   = (const float*)d_in[1];
    const float* b_t   = (const float*)d_in[2];
    const float* W_s0  = (const float*)d_in[3];
    const float* b_s0  = (const float*)d_in[4];
    const float* W_n0  = (const float*)d_in[5];
    const float* W_s1  = (const float*)d_in[6];
    const float* b_s1  = (const float*)d_in[7];
    const float* W_n1  = (const float*)d_in[8];
    const float* W_fin = (const float*)d_in[9];
    const int*   src   = (const int*)d_in[10];
    const int*   dst   = (const int*)d_in[11];
    float* out = (float*)d_out;

    const int N = in_sizes[0] / 256;   // 100000
    const int E = in_sizes[10];        // 1600000

    size_t off_b = 0;
    auto carve = [&](size_t bytes) {
        size_t cur = off_b;
        off_b = (off_b + bytes + 255) & ~(size_t)255;
        return cur;
    };
    char* base = (char*)d_ws;
    int* offs   = (int*)(base + carve((size_t)(N + 1) * 4));
    int* bcnt   = (int*)(base + carve(NBUCK_MAX * 4));
    int* boffs  = (int*)(base + carve((NBUCK_MAX + 1) * 4));
    int* cursor = (int*)(base + carve(NBUCK_MAX * 4));
    int* csr    = (int*)(base + carve((size_t)E * 4));
    unsigned long long* pairs = (unsigned long long*)(base + carve((size_t)E * 8));
    __half* wp_t  = (__half*)(base + carve((size_t)65536 * 2));
    __half* wp_l0 = (__half*)(base + carve((size_t)65536 * 2));
    __half* wp_l1 = (__half*)(base + carve((size_t)65536 * 2));
    __half* hA  = (__half*)(base + carve((size_t)N * HIDDEN * 2));
    __half* hB  = (__half*)(base + carve((size_t)N * HIDDEN * 2));
    (void)ws_size; (void)n_in; (void)out_size;

    const int nBuck = (N + (1 << BSHIFT) - 1) >> BSHIFT;   // 196

    // --- CSR build (bucketed) ---
    hipLaunchKernelGGL(zero_ints, dim3(1), dim3(256), 0, stream, bcnt, NBUCK_MAX);
    hipLaunchKernelGGL(bucket_hist, dim3((E + 4095) / 4096), dim3(256), 0, stream, dst, bcnt, E);
    hipLaunchKernelGGL(scan_buckets, dim3(1), dim3(256), 0, stream, bcnt, boffs, cursor, nBuck);
    hipLaunchKernelGGL(partition_pairs, dim3((E + 4095) / 4096), dim3(256), 0, stream,
                       src, dst, cursor, pairs, E);
    hipLaunchKernelGGL(place_csr2, dim3(nBuck), dim3(256), 0, stream, pairs, boffs, offs, csr, N, E);

    // --- weight packing (48 tiny blocks) ---
    hipLaunchKernelGGL(pack_weights, dim3(48), dim3(256), 0, stream,
                       W_t, W_s0, W_n0, W_s1, W_n1, wp_t, wp_l0, wp_l1);

    const int g32 = (N + 31) / 32;     // 3125

    // h0 = x @ W_t + b_t  (f32 burst DMA, cvt at read)
    hipLaunchKernelGGL(gemm_x32v, dim3(g32), dim3(256), 0, stream,
                       x, wp_t, b_t, hA, N);
    // layer 0 (fused gather + GEMM)
    hipLaunchKernelGGL((sage32<true, false>), dim3(g32), dim3(256), 0, stream,
                       hA, offs, csr, wp_l0, b_s0, (const float*)nullptr, (void*)hB, N);
    // layer 1 (fused gather + GEMM + final projection)
    hipLaunchKernelGGL((sage32<true, true>), dim3(g32), dim3(256), 0, stream,
                       hB, offs, csr, wp_l1, b_s1, W_fin, (void*)out, N);
}

// Round 15
// 269.073 us; speedup vs baseline: 1.1231x; 1.0305x over previous
//
#include <hip/hip_runtime.h>
#include <hip/hip_fp16.h>

#define HIDDEN 128
#define BSHIFT 9                  // 512 nodes per bucket
#define NBUCK_MAX 256

using f32x4 = __attribute__((ext_vector_type(4))) float;
using f16x8 = __attribute__((ext_vector_type(8))) _Float16;

__device__ __forceinline__ void gload16(const void* g, void* l) {
    __builtin_amdgcn_global_load_lds((const __attribute__((address_space(1))) void*)g,
                                     (__attribute__((address_space(3))) void*)l,
                                     16, 0, 0);
}

// ---------------------------------------------------------------------------
// CSR build (bucketed, no per-node global atomics)
// ---------------------------------------------------------------------------
__global__ void zero_ints(int* __restrict__ a, int n) {
    int i = blockIdx.x * 256 + threadIdx.x;
    if (i < n) a[i] = 0;
}

__launch_bounds__(256)
__global__ void bucket_hist(const int* __restrict__ dst, int* __restrict__ bcnt, int e) {
    __shared__ int c[NBUCK_MAX];
    const int t = threadIdx.x;
    c[t] = 0;
    __syncthreads();
    const int tile0 = blockIdx.x * 4096;
    const int end = min(e, tile0 + 4096);
    for (int i = tile0 + t; i < end; i += 256)
        atomicAdd(&c[dst[i] >> BSHIFT], 1);
    __syncthreads();
    if (c[t]) atomicAdd(&bcnt[t], c[t]);
}

__global__ void scan_buckets(const int* __restrict__ bcnt, int* __restrict__ boffs,
                             int* __restrict__ cursor, int nb) {
    __shared__ int sd[256];
    const int t = threadIdx.x;
    int v = (t < nb) ? bcnt[t] : 0;
    sd[t] = v;
    __syncthreads();
    for (int o = 1; o < 256; o <<= 1) {
        int add = (t >= o) ? sd[t - o] : 0;
        __syncthreads();
        sd[t] += add;
        __syncthreads();
    }
    const int ex = sd[t] - v;
    if (t < nb) { boffs[t] = ex; cursor[t] = ex; }
    if (t == nb - 1) boffs[nb] = ex + v;
}

__launch_bounds__(256)
__global__ void partition_pairs(const int* __restrict__ src, const int* __restrict__ dst,
                                int* __restrict__ cursor,
                                unsigned long long* __restrict__ pairs, int e) {
    __shared__ int cnt[NBUCK_MAX];
    __shared__ int base[NBUCK_MAX];
    const int t = threadIdx.x;
    const int tile0 = blockIdx.x * 4096;
    cnt[t] = 0;
    __syncthreads();
    int s[16], d[16], b[16];
    #pragma unroll
    for (int j = 0; j < 16; ++j) {
        const int i = tile0 + j * 256 + t;
        if (i < e) {
            d[j] = dst[i];
            s[j] = src[i];
            b[j] = d[j] >> BSHIFT;
            atomicAdd(&cnt[b[j]], 1);
        } else {
            b[j] = -1;
        }
    }
    __syncthreads();
    const int c = cnt[t];
    base[t] = c ? atomicAdd(&cursor[t], c) : 0;
    __syncthreads();
    cnt[t] = 0;
    __syncthreads();
    #pragma unroll
    for (int j = 0; j < 16; ++j) {
        if (b[j] >= 0) {
            const int r = atomicAdd(&cnt[b[j]], 1);
            pairs[(size_t)base[b[j]] + r] =
                ((unsigned long long)(unsigned)d[j] << 32) | (unsigned)s[j];
        }
    }
}

__launch_bounds__(256)
__global__ void place_csr2(const unsigned long long* __restrict__ pairs,
                           const int* __restrict__ boffs,
                           int* __restrict__ offs, int* __restrict__ csr,
                           int n, int e) {
    __shared__ int cnt[1 << BSHIFT];
    __shared__ int sc[256];
    const int b = blockIdx.x;
    const int t = threadIdx.x;
    const int node0 = b << BSHIFT;
    const int nn = min(1 << BSHIFT, n - node0);
    cnt[t] = 0;
    cnt[t + 256] = 0;
    __syncthreads();
    const int beg = boffs[b], end = boffs[b + 1];
    for (int i = beg + t; i < end; i += 256)
        atomicAdd(&cnt[(int)(pairs[i] >> 32) - node0], 1);
    __syncthreads();
    const int a0 = cnt[2 * t], a1 = cnt[2 * t + 1];
    const int s = a0 + a1;
    sc[t] = s;
    __syncthreads();
    for (int o = 1; o < 256; o <<= 1) {
        int add = (t >= o) ? sc[t - o] : 0;
        __syncthreads();
        sc[t] += add;
        __syncthreads();
    }
    const int g0 = beg + sc[t] - s;
    const int g1 = g0 + a0;
    if (2 * t < nn)     offs[node0 + 2 * t] = g0;
    if (2 * t + 1 < nn) offs[node0 + 2 * t + 1] = g1;
    __syncthreads();
    cnt[2 * t] = g0;
    cnt[2 * t + 1] = g1;
    if (node0 + nn == n && t == 0) offs[n] = e;   // sentinel
    __syncthreads();
    for (int i = beg + t; i < end; i += 256) {
        const unsigned long long pr = pairs[i];
        const int dd = (int)(pr >> 32) - node0;
        const int ss = (int)(unsigned)pr;
        const int p = atomicAdd(&cnt[dd], 1);
        csr[p] = ss;
    }
}

// ---------------------------------------------------------------------------
// Pack weights into MFMA-fragment-ordered f16 planes (Wh + Wls*32).
// ---------------------------------------------------------------------------
__global__ void pack_weights(const float* __restrict__ W_t, const float* __restrict__ Ws0,
                             const float* __restrict__ Wn0, const float* __restrict__ Ws1,
                             const float* __restrict__ Wn1,
                             __half* p_t, __half* p_l0, __half* p_l1) {
    const int bid = blockIdx.x;
    const float* W; __half* out; int b0; int S0;
    if (bid < 16)      { W = W_t; out = p_t;  b0 = 0;  S0 = 0; }
    else if (bid < 24) { W = Ws0; out = p_l0; b0 = 16; S0 = 0; }
    else if (bid < 32) { W = Wn0; out = p_l0; b0 = 24; S0 = 4; }
    else if (bid < 40) { W = Ws1; out = p_l1; b0 = 32; S0 = 0; }
    else               { W = Wn1; out = p_l1; b0 = 40; S0 = 4; }
    const int idx = (bid - b0) * 256 + threadIdx.x;
    const int step = idx >> 9;
    const int r = idx & 511;
    const int l = r & 63;
    const int col = (r >> 6) * 16 + (l & 15);
    const int k0 = step * 32 + ((l >> 4) << 3);
    const size_t o = (size_t)(S0 + step) * 4096 + (size_t)r * 8;
    #pragma unroll
    for (int j = 0; j < 8; ++j) {
        float f = W[(k0 + j) * HIDDEN + col];
        __half h = __float2half_rn(f);
        out[o + j] = h;
        out[32768 + o + j] = __float2half_rn((f - __half2float(h)) * 32.0f);
    }
}

// ---------------------------------------------------------------------------
// FUSED SAGE layer: 32 dst rows per block. A-tile K=256 = [h self | agg].
// Gather phase interleaves TWO nodes per pass (8 row-loads in flight per
// lane for the typical deg-16 pair) to double memory-level parallelism.
// Per-node accumulation order identical to R14 (bit-identical numerics).
// ---------------------------------------------------------------------------
template <bool RELU, bool FINAL>
__launch_bounds__(256, 6)
__global__ void sage32(const __half* __restrict__ h,
                       const int* __restrict__ offs, const int* __restrict__ csr,
                       const __half* __restrict__ Wp,
                       const float* __restrict__ bias,
                       const float* __restrict__ wfin,
                       void* __restrict__ outv, int nrows) {
    __shared__ __align__(16) __half As[8][2][64][8];   // 16 KB
    __shared__ float red[FINAL ? 32 : 1][4];

    const int t = threadIdx.x;
    const int lane = t & 63;
    const int w = t >> 6;
    const int blockRow0 = blockIdx.x * 32;

    // 1) self-half DMA: wave w stages step w (k = w*32..w*32+32), rt 0,1
    {
        const int kk = w * 32 + ((lane >> 4) << 3);
        #pragma unroll
        for (int rt = 0; rt < 2; ++rt) {
            const int row = min(blockRow0 + rt * 16 + (lane & 15), nrows - 1);
            gload16(h + (size_t)row * HIDDEN + kk, &As[w][rt][0][0]);
        }
    }

    // 2) gather phase: wave w aggregates nodes blockRow0 + w*8 + [0,8), 2 at a time
    {
        const int slot = lane >> 4;          // 0..3
        const int c8 = (lane & 15) * 8;      // 8 cols per lane
        #pragma unroll 1
        for (int p = 0; p < 4; ++p) {
            const int rl0 = w * 8 + p * 2;
            const int rl1 = rl0 + 1;
            const int n0 = min(blockRow0 + rl0, nrows - 1);
            const int n1 = min(blockRow0 + rl1, nrows - 1);
            const int s0 = offs[n0];
            const int d0 = offs[n0 + 1] - s0;
            const int s1 = offs[n1];
            const int d1 = offs[n1 + 1] - s1;
            float a0[8] = {0.f, 0.f, 0.f, 0.f, 0.f, 0.f, 0.f, 0.f};
            float a1[8] = {0.f, 0.f, 0.f, 0.f, 0.f, 0.f, 0.f, 0.f};
            const int dmax = max(d0, d1);
            for (int i = slot; i < dmax; i += 16) {
                int idx0[4], idx1[4];
                #pragma unroll
                for (int u = 0; u < 4; ++u) {
                    const int e = i + u * 4;
                    idx0[u] = (e < d0) ? csr[s0 + e] : -1;
                    idx1[u] = (e < d1) ? csr[s1 + e] : -1;
                }
                #pragma unroll
                for (int u = 0; u < 4; ++u) {
                    if (idx0[u] >= 0) {
                        uint4 raw = *(const uint4*)&h[(size_t)idx0[u] * HIDDEN + c8];
                        const __half2* hp = (const __half2*)&raw;
                        #pragma unroll
                        for (int m = 0; m < 4; ++m) {
                            float2 f = __half22float2(hp[m]);
                            a0[2 * m] += f.x;
                            a0[2 * m + 1] += f.y;
                        }
                    }
                    if (idx1[u] >= 0) {
                        uint4 raw = *(const uint4*)&h[(size_t)idx1[u] * HIDDEN + c8];
                        const __half2* hp = (const __half2*)&raw;
                        #pragma unroll
                        for (int m = 0; m < 4; ++m) {
                            float2 f = __half22float2(hp[m]);
                            a1[2 * m] += f.x;
                            a1[2 * m + 1] += f.y;
                        }
                    }
                }
            }
            #pragma unroll
            for (int k = 0; k < 8; ++k) {
                a0[k] += __shfl_xor(a0[k], 16, 64);
                a0[k] += __shfl_xor(a0[k], 32, 64);
                a1[k] += __shfl_xor(a1[k], 16, 64);
                a1[k] += __shfl_xor(a1[k], 32, 64);
            }
            if (slot == 0) {
                const float i0 = 1.0f / (float)max(d0, 1);
                const float i1 = 1.0f / (float)max(d1, 1);
                f16x8 v0, v1;
                #pragma unroll
                for (int j = 0; j < 8; ++j) {
                    v0[j] = (_Float16)(a0[j] * i0);
                    v1[j] = (_Float16)(a1[j] * i1);
                }
                // fragment-layout writes: lane l (cols 8l..8l+7 of row rl)
                // -> As[4+(l>>2)][rl>>4][(rl&15) + 16*(l&3)]
                *(f16x8*)&As[4 + (lane >> 2)][rl0 >> 4][(rl0 & 15) + 16 * (lane & 3)][0] = v0;
                *(f16x8*)&As[4 + (lane >> 2)][rl1 >> 4][(rl1 & 15) + 16 * (lane & 3)][0] = v1;
            }
        }
    }
    __syncthreads();   // drains DMA + gather writes; LDS read-only afterwards

    // 3) K-loop
    f32x4 acc[2][2];
    #pragma unroll
    for (int i = 0; i < 2; ++i)
        #pragma unroll
        for (int j = 0; j < 2; ++j) acc[i][j] = (f32x4){0.f, 0.f, 0.f, 0.f};

    const _Float16 S = (_Float16)0.03125f;   // 2^-5

    #pragma unroll
    for (int step = 0; step < 8; ++step) {
        const __half* wb = Wp + (size_t)step * 4096 + (w * 2) * 512 + lane * 8;
        f16x8 a[2], asr[2];
        #pragma unroll
        for (int rt = 0; rt < 2; ++rt) {
            a[rt] = *(const f16x8*)&As[step][rt][lane][0];
            asr[rt] = a[rt] * S;
        }
        #pragma unroll
        for (int c2 = 0; c2 < 2; ++c2) {
            f16x8 wh = *(const f16x8*)(wb + c2 * 512);
            f16x8 wl = *(const f16x8*)(wb + 32768 + c2 * 512);
            acc[0][c2] = __builtin_amdgcn_mfma_f32_16x16x32_f16(a[0], wh, acc[0][c2], 0, 0, 0);
            acc[1][c2] = __builtin_amdgcn_mfma_f32_16x16x32_f16(a[1], wh, acc[1][c2], 0, 0, 0);
            acc[0][c2] = __builtin_amdgcn_mfma_f32_16x16x32_f16(asr[0], wl, acc[0][c2], 0, 0, 0);
            acc[1][c2] = __builtin_amdgcn_mfma_f32_16x16x32_f16(asr[1], wl, acc[1][c2], 0, 0, 0);
        }
    }

    // 4) epilogue
    if constexpr (FINAL) {
        float part[2][4];
        #pragma unroll
        for (int rt = 0; rt < 2; ++rt)
            #pragma unroll
            for (int j = 0; j < 4; ++j) part[rt][j] = 0.f;
        #pragma unroll
        for (int c2 = 0; c2 < 2; ++c2) {
            const int col = w * 32 + c2 * 16 + (lane & 15);
            const float wf = wfin[col];
            const float bc = bias[col];
            #pragma unroll
            for (int rt = 0; rt < 2; ++rt)
                #pragma unroll
                for (int j = 0; j < 4; ++j) {
                    float v = acc[rt][c2][j] + bc;
                    if (RELU) v = fmaxf(v, 0.f);
                    part[rt][j] = fmaf(v, wf, part[rt][j]);
                }
        }
        #pragma unroll
        for (int o = 1; o < 16; o <<= 1)
            #pragma unroll
            for (int rt = 0; rt < 2; ++rt)
                #pragma unroll
                for (int j = 0; j < 4; ++j)
                    part[rt][j] += __shfl_xor(part[rt][j], o, 64);
        if ((lane & 15) == 0) {
            #pragma unroll
            for (int rt = 0; rt < 2; ++rt)
                #pragma unroll
                for (int j = 0; j < 4; ++j)
                    red[rt * 16 + ((lane >> 4) << 2) + j][w] = part[rt][j];
        }
        __syncthreads();
        if (t < 32) {
            const int r = blockRow0 + t;
            if (r < nrows)
                ((float*)outv)[r] = red[t][0] + red[t][1] + red[t][2] + red[t][3];
        }
    } else {
        __half* out = (__half*)outv;
        #pragma unroll
        for (int c2 = 0; c2 < 2; ++c2) {
            const int col = w * 32 + c2 * 16 + (lane & 15);
            const float bc = bias[col];
            #pragma unroll
            for (int rt = 0; rt < 2; ++rt) {
                const int r0 = blockRow0 + rt * 16 + ((lane >> 4) << 2);
                #pragma unroll
                for (int j = 0; j < 4; ++j) {
                    const int r = r0 + j;
                    if (r < nrows) {
                        float v = acc[rt][c2][j] + bc;
                        if (RELU) v = fmaxf(v, 0.f);
                        out[(size_t)r * HIDDEN + col] = __float2half(v);
                    }
                }
            }
        }
    }
}

// ---------------------------------------------------------------------------
// Transform GEMM (R11 winner): 32-row f32 tile (32 KB LDS), 4 waves
// col-split, single DMA burst + ONE barrier; f32->f16 cvt at read.
// ---------------------------------------------------------------------------
__launch_bounds__(256, 4)
__global__ void gemm_x32v(const float* __restrict__ X, const __half* __restrict__ Wp,
                          const float* __restrict__ bias,
                          __half* __restrict__ outp, int nrows) {
    __shared__ __align__(16) float Xs[8][2][2][64][4];   // [step][rt][half][lane][4] = 32 KB

    const int t = threadIdx.x;
    const int lane = t & 63;
    const int w = t >> 6;
    const int blockRow0 = blockIdx.x * 32;

    // burst-stage: wave w stages rt = w>>1, half = w&1 for all 8 steps (8 DMAs)
    {
        const int rt = w >> 1, hf = w & 1;
        const int row = min(blockRow0 + rt * 16 + (lane & 15), nrows - 1);
        const int k0 = ((lane >> 4) << 3) + hf * 4;
        #pragma unroll
        for (int step = 0; step < 8; ++step) {
            const float* src = X + (size_t)row * 256 + step * 32 + k0;
            gload16(src, &Xs[step][rt][hf][0][0]);
        }
    }
    __syncthreads();   // single drain

    f32x4 acc[2][2];
    #pragma unroll
    for (int i = 0; i < 2; ++i)
        #pragma unroll
        for (int j = 0; j < 2; ++j) acc[i][j] = (f32x4){0.f, 0.f, 0.f, 0.f};

    const _Float16 S = (_Float16)0.03125f;   // 2^-5

    #pragma unroll
    for (int step = 0; step < 8; ++step) {
        const __half* wb = Wp + (size_t)step * 4096 + (w * 2) * 512 + lane * 8;
        f16x8 wh[2], wl[2];
        #pragma unroll
        for (int c2 = 0; c2 < 2; ++c2) {
            wh[c2] = *(const f16x8*)(wb + c2 * 512);
            wl[c2] = *(const f16x8*)(wb + 32768 + c2 * 512);
        }
        f16x8 a[2], asr[2];
        #pragma unroll
        for (int r2 = 0; r2 < 2; ++r2) {
            f32x4 x0 = *(const f32x4*)&Xs[step][r2][0][lane][0];
            f32x4 x1 = *(const f32x4*)&Xs[step][r2][1][lane][0];
            f16x8 hh;
            #pragma unroll
            for (int j = 0; j < 4; ++j) hh[j] = (_Float16)x0[j];
            #pragma unroll
            for (int j = 0; j < 4; ++j) hh[4 + j] = (_Float16)x1[j];
            a[r2] = hh;
            asr[r2] = hh * S;
        }
        #pragma unroll
        for (int r2 = 0; r2 < 2; ++r2)
            #pragma unroll
            for (int c2 = 0; c2 < 2; ++c2) {
                acc[r2][c2] = __builtin_amdgcn_mfma_f32_16x16x32_f16(a[r2], wh[c2], acc[r2][c2], 0, 0, 0);
                acc[r2][c2] = __builtin_amdgcn_mfma_f32_16x16x32_f16(asr[r2], wl[c2], acc[r2][c2], 0, 0, 0);
            }
    }

    // epilogue: bias, fp16 h store
    #pragma unroll
    for (int c2 = 0; c2 < 2; ++c2) {
        const int col = w * 32 + c2 * 16 + (lane & 15);
        const float bc = bias[col];
        #pragma unroll
        for (int r2 = 0; r2 < 2; ++r2) {
            const int r0 = blockRow0 + r2 * 16 + ((lane >> 4) << 2);
            #pragma unroll
            for (int j = 0; j < 4; ++j) {
                const int r = r0 + j;
                if (r < nrows)
                    outp[(size_t)r * HIDDEN + col] = __float2half(acc[r2][c2][j] + bc);
            }
        }
    }
}

// ---------------------------------------------------------------------------
extern "C" void kernel_launch(void* const* d_in, const int* in_sizes, int n_in,
                              void* d_out, int out_size, void* d_ws, size_t ws_size,
                              hipStream_t stream) {
    const float* x     = (const float*)d_in[0];
    const float* W_t   = (const float*)d_in[1];
    const float* b_t   = (const float*)d_in[2];
    const float* W_s0  = (const float*)d_in[3];
    const float* b_s0  = (const float*)d_in[4];
    const float* W_n0  = (const float*)d_in[5];
    const float* W_s1  = (const float*)d_in[6];
    const float* b_s1  = (const float*)d_in[7];
    const float* W_n1  = (const float*)d_in[8];
    const float* W_fin = (const float*)d_in[9];
    const int*   src   = (const int*)d_in[10];
    const int*   dst   = (const int*)d_in[11];
    float* out = (float*)d_out;

    const int N = in_sizes[0] / 256;   // 100000
    const int E = in_sizes[10];        // 1600000

    size_t off_b = 0;
    auto carve = [&](size_t bytes) {
        size_t cur = off_b;
        off_b = (off_b + bytes + 255) & ~(size_t)255;
        return cur;
    };
    char* base = (char*)d_ws;
    int* offs   = (int*)(base + carve((size_t)(N + 1) * 4));
    int* bcnt   = (int*)(base + carve(NBUCK_MAX * 4));
    int* boffs  = (int*)(base + carve((NBUCK_MAX + 1) * 4));
    int* cursor = (int*)(base + carve(NBUCK_MAX * 4));
    int* csr    = (int*)(base + carve((size_t)E * 4));
    unsigned long long* pairs = (unsigned long long*)(base + carve((size_t)E * 8));
    __half* wp_t  = (__half*)(base + carve((size_t)65536 * 2));
    __half* wp_l0 = (__half*)(base + carve((size_t)65536 * 2));
    __half* wp_l1 = (__half*)(base + carve((size_t)65536 * 2));
    __half* hA  = (__half*)(base + carve((size_t)N * HIDDEN * 2));
    __half* hB  = (__half*)(base + carve((size_t)N * HIDDEN * 2));
    (void)ws_size; (void)n_in; (void)out_size;

    const int nBuck = (N + (1 << BSHIFT) - 1) >> BSHIFT;   // 196

    // --- CSR build (bucketed) ---
    hipLaunchKernelGGL(zero_ints, dim3(1), dim3(256), 0, stream, bcnt, NBUCK_MAX);
    hipLaunchKernelGGL(bucket_hist, dim3((E + 4095) / 4096), dim3(256), 0, stream, dst, bcnt, E);
    hipLaunchKernelGGL(scan_buckets, dim3(1), dim3(256), 0, stream, bcnt, boffs, cursor, nBuck);
    hipLaunchKernelGGL(partition_pairs, dim3((E + 4095) / 4096), dim3(256), 0, stream,
                       src, dst, cursor, pairs, E);
    hipLaunchKernelGGL(place_csr2, dim3(nBuck), dim3(256), 0, stream, pairs, boffs, offs, csr, N, E);

    // --- weight packing (48 tiny blocks) ---
    hipLaunchKernelGGL(pack_weights, dim3(48), dim3(256), 0, stream,
                       W_t, W_s0, W_n0, W_s1, W_n1, wp_t, wp_l0, wp_l1);

    const int g32 = (N + 31) / 32;     // 3125

    // h0 = x @ W_t + b_t  (f32 burst DMA, cvt at read)
    hipLaunchKernelGGL(gemm_x32v, dim3(g32), dim3(256), 0, stream,
                       x, wp_t, b_t, hA, N);
    // layer 0 (fused gather + GEMM)
    hipLaunchKernelGGL((sage32<true, false>), dim3(g32), dim3(256), 0, stream,
                       hA, offs, csr, wp_l0, b_s0, (const float*)nullptr, (void*)hB, N);
    // layer 1 (fused gather + GEMM + final projection)
    hipLaunchKernelGGL((sage32<true, true>), dim3(g32), dim3(256), 0, stream,
                       hB, offs, csr, wp_l1, b_s1, W_fin, (void*)out, N);
}